// Round 1
// baseline (53.542 us; speedup 1.0000x reference)
//
#include <hip/hip_runtime.h>
#include <hip/hip_bf16.h>

#define NVIS 16384
#define EMB 128
#define HID 64
#define MED 153
#define K1 384
#define VPB 32
#define NBLK (NVIS / VPB)   // 512 blocks
#define CAPD 1280
#define CAPP 768
#define CAPM 1024

typedef float f32x4 __attribute__((ext_vector_type(4)));
typedef short s16x8 __attribute__((ext_vector_type(8)));

__device__ __forceinline__ unsigned short f2bf(float f) {
  union { float f; unsigned u; } v; v.f = f;
  unsigned r = v.u + 0x7FFFu + ((v.u >> 16) & 1u);   // round-to-nearest-even
  return (unsigned short)(r >> 16);
}

__device__ __forceinline__ int lower_bound_dev(const int* __restrict__ a, int n, int key) {
  int lo = 0, hi = n;
  while (lo < hi) {
    int mid = (lo + hi) >> 1;
    if (a[mid] < key) lo = mid + 1; else hi = mid;
  }
  return lo;
}

__global__ __launch_bounds__(256, 2) void fused_ehr_kernel(
    const int* __restrict__ diag_codes, const int* __restrict__ diag_seg,
    const int* __restrict__ proc_codes, const int* __restrict__ proc_seg,
    const int* __restrict__ med_codes,  const int* __restrict__ med_seg,
    const float* __restrict__ diag_table, const float* __restrict__ proc_table,
    const float* __restrict__ med_table,
    const float* __restrict__ W1, const float* __restrict__ b1,
    const float* __restrict__ W2, const float* __restrict__ b2,
    float* __restrict__ out, int ND, int NP, int NM)
{
  // x tile: 32 visits x 384 k, bf16, +8 pad -> row stride 784B = 49*16B (aligned, 2-way banks)
  __shared__ __align__(16) unsigned short xs[VPB][K1 + 8];
  // h tile: 32 x 64, bf16, +8 pad -> row stride 144B = 9*16B
  __shared__ __align__(16) unsigned short hs[VPB][HID + 8];
  __shared__ int offs[3][VPB + 1];
  __shared__ int codesL[CAPD + CAPP + CAPM];

  const int tid = threadIdx.x;
  const int b0 = blockIdx.x * VPB;

  // ---- per-block segment boundaries: 3 tables x 33 boundaries = 99 binary searches ----
  if (tid < 3 * (VPB + 1)) {
    const int T = tid / (VPB + 1), idx = tid - T * (VPB + 1);
    const int* seg = (T == 0) ? diag_seg : (T == 1) ? proc_seg : med_seg;
    const int n = (T == 0) ? ND : (T == 1) ? NP : NM;
    offs[T][idx] = lower_bound_dev(seg, n, b0 + idx);
  }
  __syncthreads();

  const int sD = offs[0][0], cntD = offs[0][VPB] - sD;
  const int sP = offs[1][0], cntP = offs[1][VPB] - sP;
  const int sM = offs[2][0], cntM = offs[2][VPB] - sM;
  const bool stD = (cntD <= CAPD), stP = (cntP <= CAPP), stM = (cntM <= CAPM);

  // ---- stage this block's code windows into LDS (coalesced; uniform branches) ----
  if (stD) for (int i = tid; i < cntD; i += 256) codesL[i] = diag_codes[sD + i];
  if (stP) for (int i = tid; i < cntP; i += 256) codesL[CAPD + i] = proc_codes[sP + i];
  if (stM) for (int i = tid; i < cntM; i += 256) codesL[CAPD + CAPP + i] = med_codes[sM + i];
  __syncthreads();

  const int l = tid & 63;
  const int wv = tid >> 6;          // wave 0..3
  const int chunk = l & 31;         // float4 chunk of the 128-dim embedding
  const int slot = l >> 5;          // 2 codes in flight per wave

  // ---- gather + segment-sum: one wave per visit, 8 visits per wave ----
#define GATHER_TABLE(Tidx, TBL, CODES_G, STAGED, SGLOB, LBASE)                      \
    {                                                                               \
      const int s_ = offs[Tidx][v], e_ = offs[Tidx][v + 1];                         \
      float a0 = 0.f, a1 = 0.f, a2 = 0.f, a3 = 0.f;                                 \
      if (STAGED) {                                                                 \
        for (int i = s_ + slot; i < e_; i += 2) {                                   \
          const int c = codesL[LBASE + (i - SGLOB)];                                \
          const f32x4 t = *(const f32x4*)(TBL + (size_t)c * EMB + chunk * 4);       \
          a0 += t[0]; a1 += t[1]; a2 += t[2]; a3 += t[3];                           \
        }                                                                           \
      } else {                                                                      \
        for (int i = s_ + slot; i < e_; i += 2) {                                   \
          const int c = CODES_G[i];                                                 \
          const f32x4 t = *(const f32x4*)(TBL + (size_t)c * EMB + chunk * 4);       \
          a0 += t[0]; a1 += t[1]; a2 += t[2]; a3 += t[3];                           \
        }                                                                           \
      }                                                                             \
      a0 += __shfl_xor(a0, 32); a1 += __shfl_xor(a1, 32);                           \
      a2 += __shfl_xor(a2, 32); a3 += __shfl_xor(a3, 32);                           \
      if (slot == 0) {                                                              \
        unsigned p0 = (unsigned)f2bf(a0) | ((unsigned)f2bf(a1) << 16);              \
        unsigned p1 = (unsigned)f2bf(a2) | ((unsigned)f2bf(a3) << 16);              \
        unsigned* dst_ = (unsigned*)&xs[v][Tidx * EMB + chunk * 4];                 \
        dst_[0] = p0; dst_[1] = p1;                                                 \
      }                                                                             \
    }

  #pragma unroll 1
  for (int it = 0; it < VPB / 4; ++it) {
    const int v = wv * (VPB / 4) + it;
    GATHER_TABLE(0, diag_table, diag_codes, stD, sD, 0)
    GATHER_TABLE(1, proc_table, proc_codes, stP, sP, CAPD)
    GATHER_TABLE(2, med_table,  med_codes,  stM, sM, CAPD + CAPP)
  }
  __syncthreads();

  // ---- GEMM1: h[32][64] = relu(x[32][384] @ W1[384][64] + b1), bf16 MFMA 16x16x32 ----
  // Wave w owns output cols [w*16, w*16+16). A frag: row=l&15, k=(l>>4)*8+e.
  // B frag: col=l&15, k=(l>>4)*8+e. D: col=l&15, row=(l>>4)*4+reg (m89-verified).
  const int jloc = l & 15;
  const int kq = l >> 4;
  const int j1 = wv * 16 + jloc;

  s16x8 bfr[12];
  #pragma unroll
  for (int kt = 0; kt < 12; ++kt) {
    const int kb = kt * 32 + kq * 8;
    s16x8 bf;
    #pragma unroll
    for (int e = 0; e < 8; ++e)
      bf[e] = (short)f2bf(W1[(kb + e) * HID + j1]);
    bfr[kt] = bf;
  }

  f32x4 acc0 = {0.f, 0.f, 0.f, 0.f};
  f32x4 acc1 = {0.f, 0.f, 0.f, 0.f};
  #pragma unroll
  for (int kt = 0; kt < 12; ++kt) {
    const int ko = kt * 32 + kq * 8;
    const s16x8 a0 = *(const s16x8*)&xs[jloc][ko];
    const s16x8 a1 = *(const s16x8*)&xs[jloc + 16][ko];
    acc0 = __builtin_amdgcn_mfma_f32_16x16x32_bf16(a0, bfr[kt], acc0, 0, 0, 0);
    acc1 = __builtin_amdgcn_mfma_f32_16x16x32_bf16(a1, bfr[kt], acc1, 0, 0, 0);
  }

  {
    const float bias1 = b1[j1];
    #pragma unroll
    for (int r = 0; r < 4; ++r) {
      const int vr = kq * 4 + r;
      hs[vr][j1]      = f2bf(fmaxf(acc0[r] + bias1, 0.f));
      hs[vr + 16][j1] = f2bf(fmaxf(acc1[r] + bias1, 0.f));
    }
  }
  __syncthreads();

  // ---- GEMM2: out[32][153] = sigmoid(h[32][64] @ W2[64][153] + b2) ----
  // N padded to 160 -> 10 tiles of 16; wave w takes tiles w, w+4, w+8.
  for (int t = wv; t < 10; t += 4) {
    const int n = t * 16 + jloc;
    const bool nok = (n < MED);
    s16x8 bw0, bw1;
    #pragma unroll
    for (int e = 0; e < 8; ++e) {
      const int k0 = kq * 8 + e;
      bw0[e] = nok ? (short)f2bf(W2[k0 * MED + n])        : (short)0;
      bw1[e] = nok ? (short)f2bf(W2[(k0 + 32) * MED + n]) : (short)0;
    }
    f32x4 o0 = {0.f, 0.f, 0.f, 0.f};
    f32x4 o1 = {0.f, 0.f, 0.f, 0.f};
    {
      const int ko = kq * 8;
      const s16x8 a00 = *(const s16x8*)&hs[jloc][ko];
      const s16x8 a10 = *(const s16x8*)&hs[jloc + 16][ko];
      o0 = __builtin_amdgcn_mfma_f32_16x16x32_bf16(a00, bw0, o0, 0, 0, 0);
      o1 = __builtin_amdgcn_mfma_f32_16x16x32_bf16(a10, bw0, o1, 0, 0, 0);
      const s16x8 a01 = *(const s16x8*)&hs[jloc][ko + 32];
      const s16x8 a11 = *(const s16x8*)&hs[jloc + 16][ko + 32];
      o0 = __builtin_amdgcn_mfma_f32_16x16x32_bf16(a01, bw1, o0, 0, 0, 0);
      o1 = __builtin_amdgcn_mfma_f32_16x16x32_bf16(a11, bw1, o1, 0, 0, 0);
    }
    if (nok) {
      const float bias2 = b2[n];
      #pragma unroll
      for (int r = 0; r < 4; ++r) {
        const int row = kq * 4 + r;
        const float z0 = o0[r] + bias2;
        const float z1 = o1[r] + bias2;
        out[(size_t)(b0 + row) * MED + n]      = 1.f / (1.f + __expf(-z0));
        out[(size_t)(b0 + row + 16) * MED + n] = 1.f / (1.f + __expf(-z1));
      }
    }
  }
}

extern "C" void kernel_launch(void* const* d_in, const int* in_sizes, int n_in,
                              void* d_out, int out_size, void* d_ws, size_t ws_size,
                              hipStream_t stream) {
  const int* diag_codes = (const int*)d_in[0];
  const int* diag_seg   = (const int*)d_in[1];
  const int* proc_codes = (const int*)d_in[2];
  const int* proc_seg   = (const int*)d_in[3];
  const int* med_codes  = (const int*)d_in[4];
  const int* med_seg    = (const int*)d_in[5];
  const float* diag_table = (const float*)d_in[6];
  const float* proc_table = (const float*)d_in[7];
  const float* med_table  = (const float*)d_in[8];
  const float* W1 = (const float*)d_in[9];
  const float* b1 = (const float*)d_in[10];
  const float* W2 = (const float*)d_in[11];
  const float* b2 = (const float*)d_in[12];
  float* out = (float*)d_out;

  fused_ehr_kernel<<<dim3(NBLK), dim3(256), 0, stream>>>(
      diag_codes, diag_seg, proc_codes, proc_seg, med_codes, med_seg,
      diag_table, proc_table, med_table, W1, b1, W2, b2, out,
      in_sizes[0], in_sizes[2], in_sizes[4]);
}

// Round 2
// 37.419 us; speedup vs baseline: 1.4309x; 1.4309x over previous
//
#include <hip/hip_runtime.h>
#include <hip/hip_bf16.h>

#define NVIS 16384
#define EMB 128
#define HID 64
#define MED 153
#define K1 384
#define VPB 16
#define NBLK (NVIS / VPB)   // 1024 blocks -> 4 blocks/CU, all co-resident
#define CAPD 640
#define CAPP 384
#define CAPM 512
#define CAPT (CAPD + CAPP + CAPM)

typedef float f32x4 __attribute__((ext_vector_type(4)));
typedef short s16x8 __attribute__((ext_vector_type(8)));

__device__ __forceinline__ unsigned short f2bf(float f) {
  union { float f; unsigned u; } v; v.f = f;
  unsigned r = v.u + 0x7FFFu + ((v.u >> 16) & 1u);   // round-to-nearest-even
  return (unsigned short)(r >> 16);
}

__device__ __forceinline__ int lower_bound_rng(const int* __restrict__ a, int lo, int hi, int key) {
  while (lo < hi) {
    int mid = (lo + hi) >> 1;
    if (a[mid] < key) lo = mid + 1; else hi = mid;
  }
  return lo;
}

// interpolation-bracketed lower_bound: seg values ~uniform over [0,16384)
__device__ __forceinline__ int lower_bound_fast(const int* __restrict__ a, int n, int key) {
  long long g = ((long long)key * (long long)n) >> 14;   // key * n / 16384
  int L = (int)g - 3072, R = (int)g + 3072;
  if (L < 0) L = 0;
  if (R > n) R = n;
  const bool ok = (L == 0 || a[L - 1] < key) && (R == n || a[R] >= key);
  if (!ok) { L = 0; R = n; }   // fallback: full range (always correct)
  return lower_bound_rng(a, L, R, key);
}

__global__ __launch_bounds__(256, 4) void fused_ehr_kernel(
    const int* __restrict__ diag_codes, const int* __restrict__ diag_seg,
    const int* __restrict__ proc_codes, const int* __restrict__ proc_seg,
    const int* __restrict__ med_codes,  const int* __restrict__ med_seg,
    const float* __restrict__ diag_table, const float* __restrict__ proc_table,
    const float* __restrict__ med_table,
    const float* __restrict__ W1, const float* __restrict__ b1,
    const float* __restrict__ W2, const float* __restrict__ b2,
    float* __restrict__ out, int ND, int NP, int NM)
{
  // x tile: 16 visits x 384 k, bf16, +8 pad -> row stride 784B
  __shared__ __align__(16) unsigned short xs[VPB][K1 + 8];
  // h tile: 16 x 64, bf16, +8 pad
  __shared__ __align__(16) unsigned short hs[VPB][HID + 8];
  __shared__ int offs[3][VPB + 1];
  __shared__ int codesL[CAPT];
  __shared__ int segL[CAPT];

  const int tid = threadIdx.x;
  const int b0 = blockIdx.x * VPB;

  // ---- 6 end-boundary searches (2 per table) ----
  if (tid < 6) {
    const int T = tid >> 1, w = tid & 1;
    const int* seg = (T == 0) ? diag_seg : (T == 1) ? proc_seg : med_seg;
    const int n = (T == 0) ? ND : (T == 1) ? NP : NM;
    offs[T][w ? VPB : 0] = lower_bound_fast(seg, n, b0 + (w ? VPB : 0));
  }
  __syncthreads();

  const int sD = offs[0][0], cntD = offs[0][VPB] - sD;
  const int sP = offs[1][0], cntP = offs[1][VPB] - sP;
  const int sM = offs[2][0], cntM = offs[2][VPB] - sM;
  const bool stD = (cntD <= CAPD), stP = (cntP <= CAPP), stM = (cntM <= CAPM);

  // init interior boundaries to e (correct when no staged element >= key)
  if (tid < 3 * (VPB - 1)) {
    const int T = tid / (VPB - 1), idx = tid - T * (VPB - 1) + 1;
    offs[T][idx] = offs[T][VPB];
  }
  // stage code + seg windows (coalesced)
  if (stD) for (int i = tid; i < cntD; i += 256) { codesL[i] = diag_codes[sD + i]; segL[i] = diag_seg[sD + i]; }
  if (stP) for (int i = tid; i < cntP; i += 256) { codesL[CAPD + i] = proc_codes[sP + i]; segL[CAPD + i] = proc_seg[sP + i]; }
  if (stM) for (int i = tid; i < cntM; i += 256) { codesL[CAPD + CAPP + i] = med_codes[sM + i]; segL[CAPD + CAPP + i] = med_seg[sM + i]; }
  __syncthreads();

  // ---- interior boundary marking from staged seg window (conflict-free) ----
#define MARK(Tidx, STAGED, CNT, SBASE, LBASE, SEGG, NT)                          \
  if (STAGED) {                                                                  \
    for (int i = tid; i < CNT; i += 256) {                                       \
      const int v1 = segL[LBASE + i];                                            \
      const int v0 = (i == 0) ? (b0 - 1) : segL[LBASE + i - 1];                  \
      int klo = v0 + 1; if (klo < b0 + 1) klo = b0 + 1;                          \
      int khi = v1;     if (khi > b0 + VPB - 1) khi = b0 + VPB - 1;              \
      for (int k = klo; k <= khi; ++k) offs[Tidx][k - b0] = SBASE + i;           \
    }                                                                            \
  } else if (tid < VPB - 1) {                                                    \
    offs[Tidx][tid + 1] = lower_bound_fast(SEGG, NT, b0 + tid + 1);              \
  }

  MARK(0, stD, cntD, sD, 0,           diag_seg, ND)
  MARK(1, stP, cntP, sP, CAPD,        proc_seg, NP)
  MARK(2, stM, cntM, sM, CAPD + CAPP, med_seg,  NM)
  __syncthreads();

  const int l = tid & 63;
  const int wv = tid >> 6;          // wave 0..3
  const int chunk = l & 31;         // float4 chunk of the 128-dim embedding
  const int slot = l >> 5;          // 2 code-slots per wave

  // ---- gather + segment-sum: one wave per visit, 4 visits per wave ----
  // staged path is 4x unrolled: 4 independent dwordx4 loads in flight per lane
#define GATHER_TABLE(Tidx, TBL, CODES_G, STAGED, SGLOB, LBASE)                      \
    {                                                                               \
      const int s_ = offs[Tidx][v], e_ = offs[Tidx][v + 1];                         \
      float a0 = 0.f, a1 = 0.f, a2 = 0.f, a3 = 0.f;                                 \
      int i = s_ + slot;                                                            \
      if (STAGED) {                                                                 \
        const int lb = LBASE - SGLOB;                                               \
        for (; i + 6 < e_; i += 8) {                                                \
          const int c0 = codesL[lb + i];                                            \
          const int c1 = codesL[lb + i + 2];                                        \
          const int c2 = codesL[lb + i + 4];                                        \
          const int c3 = codesL[lb + i + 6];                                        \
          const f32x4 t0 = *(const f32x4*)(TBL + (size_t)c0 * EMB + chunk * 4);     \
          const f32x4 t1 = *(const f32x4*)(TBL + (size_t)c1 * EMB + chunk * 4);     \
          const f32x4 t2 = *(const f32x4*)(TBL + (size_t)c2 * EMB + chunk * 4);     \
          const f32x4 t3 = *(const f32x4*)(TBL + (size_t)c3 * EMB + chunk * 4);     \
          a0 += (t0[0] + t1[0]) + (t2[0] + t3[0]);                                  \
          a1 += (t0[1] + t1[1]) + (t2[1] + t3[1]);                                  \
          a2 += (t0[2] + t1[2]) + (t2[2] + t3[2]);                                  \
          a3 += (t0[3] + t1[3]) + (t2[3] + t3[3]);                                  \
        }                                                                           \
        for (; i < e_; i += 2) {                                                    \
          const int c = codesL[lb + i];                                             \
          const f32x4 t = *(const f32x4*)(TBL + (size_t)c * EMB + chunk * 4);       \
          a0 += t[0]; a1 += t[1]; a2 += t[2]; a3 += t[3];                           \
        }                                                                           \
      } else {                                                                      \
        for (; i < e_; i += 2) {                                                    \
          const int c = CODES_G[i];                                                 \
          const f32x4 t = *(const f32x4*)(TBL + (size_t)c * EMB + chunk * 4);       \
          a0 += t[0]; a1 += t[1]; a2 += t[2]; a3 += t[3];                           \
        }                                                                           \
      }                                                                             \
      a0 += __shfl_xor(a0, 32); a1 += __shfl_xor(a1, 32);                           \
      a2 += __shfl_xor(a2, 32); a3 += __shfl_xor(a3, 32);                           \
      if (slot == 0) {                                                              \
        unsigned p0 = (unsigned)f2bf(a0) | ((unsigned)f2bf(a1) << 16);              \
        unsigned p1 = (unsigned)f2bf(a2) | ((unsigned)f2bf(a3) << 16);              \
        unsigned* dst_ = (unsigned*)&xs[v][Tidx * EMB + chunk * 4];                 \
        dst_[0] = p0; dst_[1] = p1;                                                 \
      }                                                                             \
    }

  #pragma unroll 1
  for (int it = 0; it < VPB / 4; ++it) {
    const int v = wv * (VPB / 4) + it;
    GATHER_TABLE(0, diag_table, diag_codes, stD, sD, 0)
    GATHER_TABLE(1, proc_table, proc_codes, stP, sP, CAPD)
    GATHER_TABLE(2, med_table,  med_codes,  stM, sM, CAPD + CAPP)
  }
  __syncthreads();

  // ---- GEMM1: h[16][64] = relu(x[16][384] @ W1[384][64] + b1), bf16 MFMA 16x16x32 ----
  // Wave w owns output cols [w*16, w*16+16). A frag: row=l&15, k=(l>>4)*8+e.
  // B frag: col=l&15, k=(l>>4)*8+e. D: col=l&15, row=(l>>4)*4+reg (m89-verified).
  const int jloc = l & 15;
  const int kq = l >> 4;
  const int j1 = wv * 16 + jloc;

  s16x8 bfr[12];
  #pragma unroll
  for (int kt = 0; kt < 12; ++kt) {
    const int kb = kt * 32 + kq * 8;
    s16x8 bf;
    #pragma unroll
    for (int e = 0; e < 8; ++e)
      bf[e] = (short)f2bf(W1[(kb + e) * HID + j1]);
    bfr[kt] = bf;
  }

  f32x4 acc = {0.f, 0.f, 0.f, 0.f};
  #pragma unroll
  for (int kt = 0; kt < 12; ++kt) {
    const int ko = kt * 32 + kq * 8;
    const s16x8 a0 = *(const s16x8*)&xs[jloc][ko];
    acc = __builtin_amdgcn_mfma_f32_16x16x32_bf16(a0, bfr[kt], acc, 0, 0, 0);
  }

  {
    const float bias1 = b1[j1];
    #pragma unroll
    for (int r = 0; r < 4; ++r) {
      const int vr = kq * 4 + r;
      hs[vr][j1] = f2bf(fmaxf(acc[r] + bias1, 0.f));
    }
  }
  __syncthreads();

  // ---- GEMM2: out[16][153] = sigmoid(h[16][64] @ W2[64][153] + b2) ----
  // N padded to 160 -> 10 tiles of 16; wave w takes tiles w, w+4, w+8.
  for (int t = wv; t < 10; t += 4) {
    const int n = t * 16 + jloc;
    const bool nok = (n < MED);
    s16x8 bw0, bw1;
    #pragma unroll
    for (int e = 0; e < 8; ++e) {
      const int k0 = kq * 8 + e;
      bw0[e] = nok ? (short)f2bf(W2[k0 * MED + n])        : (short)0;
      bw1[e] = nok ? (short)f2bf(W2[(k0 + 32) * MED + n]) : (short)0;
    }
    f32x4 o0 = {0.f, 0.f, 0.f, 0.f};
    {
      const int ko = kq * 8;
      const s16x8 a00 = *(const s16x8*)&hs[jloc][ko];
      o0 = __builtin_amdgcn_mfma_f32_16x16x32_bf16(a00, bw0, o0, 0, 0, 0);
      const s16x8 a01 = *(const s16x8*)&hs[jloc][ko + 32];
      o0 = __builtin_amdgcn_mfma_f32_16x16x32_bf16(a01, bw1, o0, 0, 0, 0);
    }
    if (nok) {
      const float bias2 = b2[n];
      #pragma unroll
      for (int r = 0; r < 4; ++r) {
        const int row = kq * 4 + r;
        const float z0 = o0[r] + bias2;
        out[(size_t)(b0 + row) * MED + n] = 1.f / (1.f + __expf(-z0));
      }
    }
  }
}

extern "C" void kernel_launch(void* const* d_in, const int* in_sizes, int n_in,
                              void* d_out, int out_size, void* d_ws, size_t ws_size,
                              hipStream_t stream) {
  const int* diag_codes = (const int*)d_in[0];
  const int* diag_seg   = (const int*)d_in[1];
  const int* proc_codes = (const int*)d_in[2];
  const int* proc_seg   = (const int*)d_in[3];
  const int* med_codes  = (const int*)d_in[4];
  const int* med_seg    = (const int*)d_in[5];
  const float* diag_table = (const float*)d_in[6];
  const float* proc_table = (const float*)d_in[7];
  const float* med_table  = (const float*)d_in[8];
  const float* W1 = (const float*)d_in[9];
  const float* b1 = (const float*)d_in[10];
  const float* W2 = (const float*)d_in[11];
  const float* b2 = (const float*)d_in[12];
  float* out = (float*)d_out;

  fused_ehr_kernel<<<dim3(NBLK), dim3(256), 0, stream>>>(
      diag_codes, diag_seg, proc_codes, proc_seg, med_codes, med_seg,
      diag_table, proc_table, med_table, W1, b1, W2, b2, out,
      in_sizes[0], in_sizes[2], in_sizes[4]);
}